// Round 4
// baseline (926.680 us; speedup 1.0000x reference)
//
#include <hip/hip_runtime.h>
#include <hip/hip_bf16.h>
#include <cstdint>

// BalancedMamba on MI355X — round 4: bf16 intermediates + pre-converted
// weights + LDS-staged B/C in scans. fp32 residual stream h and scan state.
// B=16 L=4096 DIN=1280 DM=128 N=16 R=8 NL=2
#define B_   16
#define L_   4096
#define DIN_ 1280
#define DM_  128
#define NS_  16
#define RR_  8
#define NL_  2
#define M_   (B_ * L_)      // 65536 tokens
#define NC_  128            // scan chunks over L
#define CL_  (L_ / NC_)     // 32 steps per chunk

typedef short short8 __attribute__((ext_vector_type(8)));
typedef float f32x4  __attribute__((ext_vector_type(4)));
typedef unsigned short ushort;
typedef ushort ushort4v __attribute__((ext_vector_type(4)));
typedef ushort ushort8v __attribute__((ext_vector_type(8)));

__device__ __forceinline__ float silu_f(float x) { return x / (1.f + __expf(-x)); }

__device__ __forceinline__ ushort f2bf(float f) {   // RNE fp32 -> bf16
  union { float f; uint32_t u; } v; v.f = f;
  uint32_t u = v.u;
  u += 0x7fffu + ((u >> 16) & 1u);
  return (ushort)(u >> 16);
}
__device__ __forceinline__ float bf2f(ushort h) {
  union { uint32_t u; float f; } v; v.u = ((uint32_t)h) << 16; return v.f;
}

// f32 -> bf16 bulk converter (weights). n % 4 == 0.
__global__ __launch_bounds__(256) void wcvt(
    const float* __restrict__ src, ushort* __restrict__ dst, int n)
{
  int i = (blockIdx.x * 256 + threadIdx.x) * 4;
  if (i < n) {
    float4 v = *(const float4*)(src + i);
    ushort4v o = { f2bf(v.x), f2bf(v.y), f2bf(v.z), f2bf(v.w) };
    *(ushort4v*)(dst + i) = o;
  }
}

// ---------------------------------------------------------------------------
// bf16-MFMA GEMM: C[m,n] = sum_k A[m,k]*W[n,k] (+bias).
// A: fp32 (Af, converted in staging) or bf16 (Ab, direct). W: bf16.
// 128x128 tile, BK=32, 4 waves, 16x16x32 MFMA 4x4 grid per wave.
// cols < split -> C0 (fp32 C0f w/ optional residual, or bf16 C0b);
// cols >= split -> C1b bf16 with silu. split % 128 == 0.
// ---------------------------------------------------------------------------
#define LDK 40   // padded LDS row stride in shorts

__global__ __launch_bounds__(256) void gemm_bf(
    const float* __restrict__ Af, const ushort* __restrict__ Ab,
    const ushort* __restrict__ Wb, const float* __restrict__ bias,
    float* __restrict__ C0f, ushort* __restrict__ C0b, ushort* __restrict__ C1b,
    int Ncols, int K, int split, int residual)
{
  __shared__ ushort As[128 * LDK];
  __shared__ ushort Ws[128 * LDK];
  const int tid = threadIdx.x;
  const int n0 = blockIdx.x * 128;
  const int m0 = blockIdx.y * 128;
  const int srow = tid >> 1;
  const int scol = (tid & 1) << 4;          // 0 or 16
  const bool abf = (Ab != nullptr);
  const float*  gAf = Af + (size_t)(m0 + srow) * K + scol;
  const ushort* gAb = Ab + (size_t)(m0 + srow) * K + scol;
  const ushort* gW  = Wb + (size_t)(n0 + srow) * K + scol;

  const int lane = tid & 63;
  const int wv = tid >> 6;
  const int wm = (wv & 1) * 64, wn = (wv >> 1) * 64;
  const int ln15 = lane & 15, quad = lane >> 4;

  f32x4 acc[4][4];
#pragma unroll
  for (int i = 0; i < 4; ++i)
#pragma unroll
    for (int j = 0; j < 4; ++j) acc[i][j] = (f32x4){0.f, 0.f, 0.f, 0.f};

  float4 fa[4];
  ushort8v ba0, ba1, bw0, bw1;
  if (abf) { ba0 = *(const ushort8v*)gAb; ba1 = *(const ushort8v*)(gAb + 8); }
  else {
#pragma unroll
    for (int j = 0; j < 4; ++j) fa[j] = *(const float4*)(gAf + j * 4);
  }
  bw0 = *(const ushort8v*)gW; bw1 = *(const ushort8v*)(gW + 8);

  for (int k0 = 0; k0 < K; k0 += 32) {
    __syncthreads();
    if (abf) {
      *(ushort8v*)&As[srow * LDK + scol]     = ba0;
      *(ushort8v*)&As[srow * LDK + scol + 8] = ba1;
    } else {
#pragma unroll
      for (int j = 0; j < 4; ++j) {
        ushort4v a4 = { f2bf(fa[j].x), f2bf(fa[j].y), f2bf(fa[j].z), f2bf(fa[j].w) };
        *(ushort4v*)&As[srow * LDK + scol + j * 4] = a4;
      }
    }
    *(ushort8v*)&Ws[srow * LDK + scol]     = bw0;
    *(ushort8v*)&Ws[srow * LDK + scol + 8] = bw1;
    if (k0 + 32 < K) {
      if (abf) {
        ba0 = *(const ushort8v*)(gAb + k0 + 32);
        ba1 = *(const ushort8v*)(gAb + k0 + 40);
      } else {
#pragma unroll
        for (int j = 0; j < 4; ++j) fa[j] = *(const float4*)(gAf + k0 + 32 + j * 4);
      }
      bw0 = *(const ushort8v*)(gW + k0 + 32);
      bw1 = *(const ushort8v*)(gW + k0 + 40);
    }
    __syncthreads();
    short8 aF[4], bF[4];
#pragma unroll
    for (int mt = 0; mt < 4; ++mt)
      aF[mt] = *(const short8*)&As[(wm + mt * 16 + ln15) * LDK + quad * 8];
#pragma unroll
    for (int nt = 0; nt < 4; ++nt)
      bF[nt] = *(const short8*)&Ws[(wn + nt * 16 + ln15) * LDK + quad * 8];
#pragma unroll
    for (int mt = 0; mt < 4; ++mt)
#pragma unroll
      for (int nt = 0; nt < 4; ++nt)
        acc[mt][nt] = __builtin_amdgcn_mfma_f32_16x16x32_bf16(
            aF[mt], bF[nt], acc[mt][nt], 0, 0, 0);
  }

  // C/D layout: col=lane&15, row=quad*4+reg  [m89/m91-verified]
  const bool left = n0 < split;   // block-uniform
#pragma unroll
  for (int mt = 0; mt < 4; ++mt) {
    const int row = m0 + wm + mt * 16 + quad * 4;
#pragma unroll
    for (int nt = 0; nt < 4; ++nt) {
      const int col = n0 + wn + nt * 16 + ln15;
      const float bv = bias ? bias[col] : 0.f;
#pragma unroll
      for (int r = 0; r < 4; ++r) {
        float v = acc[mt][nt][r] + bv;
        const int rr = row + r;
        if (left) {
          if (C0f) {
            float* p = C0f + (size_t)rr * split + col;
            if (residual) v += *p;
            *p = v;
          } else {
            C0b[(size_t)rr * split + col] = f2bf(v);
          }
        } else {
          C1b[(size_t)rr * (Ncols - split) + (col - split)] = f2bf(silu_f(v));
        }
      }
    }
  }
}

// ---------------------------------------------------------------------------
// Fused depthwise causal conv(k=2)+silu -> u, x_proj(40x128)->[dt;B;C],
// dt_proj(128x8)+softplus. bf16 in/out. Block = 256 thr, 32 tokens.
// ---------------------------------------------------------------------------
__global__ __launch_bounds__(256) void xpc(
    const ushort* __restrict__ uraw,  // [M,128] bf16 pre-conv
    const float* __restrict__ cw, const float* __restrict__ cb,
    const float* __restrict__ xpw,    // [40,128]
    const float* __restrict__ dtw,    // [128,8]
    const float* __restrict__ dtb,    // [128]
    ushort* __restrict__ uout,        // [M,128] bf16 post-conv
    ushort* __restrict__ delta,       // [M,128] bf16
    ushort* __restrict__ bcout)       // [M,32]  bf16
{
  __shared__ float u_s[32][132];
  __shared__ float xp_s[40 * 128];
  __shared__ float dtw_s[128 * 8];
  __shared__ float dtb_s[128];
  __shared__ float proj_s[32][41];
  const int tid = threadIdx.x;
  const size_t m0 = (size_t)blockIdx.x * 32;
  const int t0 = (int)(m0 & (L_ - 1));

#pragma unroll
  for (int i = 0; i < 16; ++i) {     // conv + silu
    int f = tid + i * 256;
    int tok = f >> 7, dd = f & 127;
    float cur = bf2f(uraw[(m0 + tok) * DM_ + dd]);
    float prev = (t0 + tok > 0) ? bf2f(uraw[(m0 + tok - 1) * DM_ + dd]) : 0.f;
    float v = silu_f(cw[dd * 2] * prev + cw[dd * 2 + 1] * cur + cb[dd]);
    u_s[tok][dd] = v;
    uout[(m0 + tok) * DM_ + dd] = f2bf(v);
  }
  for (int f = tid; f < 40 * 128; f += 256) xp_s[f] = xpw[f];
  for (int f = tid; f < 128 * 8; f += 256) dtw_s[f] = dtw[f];
  if (tid < 128) dtb_s[tid] = dtb[tid];
  __syncthreads();

  {  // proj[tok][e] = u_row . xp_w[e]
    const int tok = tid & 31, eg = tid >> 5;
    float pa[5] = {0.f, 0.f, 0.f, 0.f, 0.f};
    for (int dd = 0; dd < 128; dd += 4) {
      float4 uu = *(const float4*)&u_s[tok][dd];
#pragma unroll
      for (int i = 0; i < 5; ++i) {
        float4 xv = *(const float4*)&xp_s[(eg * 5 + i) * 128 + dd];
        pa[i] += uu.x * xv.x + uu.y * xv.y + uu.z * xv.z + uu.w * xv.w;
      }
    }
#pragma unroll
    for (int i = 0; i < 5; ++i) proj_s[tok][eg * 5 + i] = pa[i];
  }
  __syncthreads();

#pragma unroll
  for (int i = 0; i < 4; ++i) {      // B,C -> [M,32] bf16
    int f = tid + i * 256;
    bcout[m0 * 32 + f] = f2bf(proj_s[f >> 5][8 + (f & 31)]);
  }

  {  // delta = softplus(proj[0:8] . dt_w + dt_b)
    const int tok = tid & 31, dg = tid >> 5;
    float pr[8];
#pragma unroll
    for (int r = 0; r < 8; ++r) pr[r] = proj_s[tok][r];
#pragma unroll
    for (int jj = 0; jj < 16; ++jj) {
      int dd = dg * 16 + jj;
      float acc = dtb_s[dd];
#pragma unroll
      for (int r = 0; r < 8; ++r) acc += pr[r] * dtw_s[dd * 8 + r];
      float sp = (acc > 20.f) ? acc : log1pf(__expf(acc));
      u_s[tok][dd] = sp;
    }
  }
  __syncthreads();
#pragma unroll
  for (int i = 0; i < 16; ++i) {
    int f = tid + i * 256;
    delta[(m0 + (f >> 7)) * DM_ + (f & 127)] = f2bf(u_s[f >> 7][f & 127]);
  }
}

// ---------------------------------------------------------------------------
// Scan phase 1: per-chunk h from 0 (register h[16]); stores h_end and
// S=sum(delta) (chunk decay = exp(A_n*S)). Thread = d, block = (chunk,b).
// BC chunk staged to LDS once (broadcast reads in-loop).
// ---------------------------------------------------------------------------
__global__ __launch_bounds__(128) void scan_h(
    const ushort* __restrict__ delta, const ushort* __restrict__ u,
    const ushort* __restrict__ BCb, const float* __restrict__ alog,
    float* __restrict__ hend, float* __restrict__ Ssum)
{
  __shared__ float bcs[CL_][32];
  const int d = threadIdx.x;
  const int chunk = blockIdx.x, b = blockIdx.y;
  const size_t rowbase = (size_t)b * L_ + (size_t)chunk * CL_;
  {
    ushort8v v = *(const ushort8v*)(BCb + rowbase * 32 + (size_t)d * 8);
    float* dst = &bcs[0][0] + d * 8;
#pragma unroll
    for (int j = 0; j < 8; ++j) dst[j] = bf2f(v[j]);
  }
  float a[NS_], h[NS_];
#pragma unroll
  for (int n = 0; n < NS_; ++n) {
    a[n] = -__expf(alog[d * NS_ + n]);
    h[n] = 0.f;
  }
  float S = 0.f;
  __syncthreads();
  float dlt = bf2f(delta[rowbase * DM_ + d]);
  float uu  = bf2f(u[rowbase * DM_ + d]);
  for (int s = 0; s < CL_; ++s) {
    float dn = 0.f, un = 0.f;
    if (s + 1 < CL_) {
      dn = bf2f(delta[(rowbase + s + 1) * DM_ + d]);
      un = bf2f(u[(rowbase + s + 1) * DM_ + d]);
    }
    float Bv[NS_];
#pragma unroll
    for (int q = 0; q < 4; ++q)
      *(float4*)&Bv[q * 4] = *(const float4*)&bcs[s][q * 4];
    const float du = dlt * uu;
    S += dlt;
#pragma unroll
    for (int n = 0; n < NS_; ++n) {
      float dA = __expf(dlt * a[n]);
      h[n] = fmaf(h[n], dA, du * Bv[n]);
    }
    dlt = dn; uu = un;
  }
  const size_t o = ((size_t)b * NC_ + chunk) * DM_ + d;
  float4* hp = (float4*)(hend + o * NS_);
#pragma unroll
  for (int q = 0; q < 4; ++q)
    hp[q] = make_float4(h[q * 4], h[q * 4 + 1], h[q * 4 + 2], h[q * 4 + 3]);
  Ssum[o] = S;
}

// phase 2: sequential chunk combine, software-pipelined loads.
__global__ __launch_bounds__(256) void scan_comb(
    const float* __restrict__ hend, const float* __restrict__ Ssum,
    const float* __restrict__ alog, float* __restrict__ hstart)
{
  const int idx = blockIdx.x * 256 + threadIdx.x;   // B*DM*NS
  const int n = idx & 15;
  const int d = (idx >> 4) & 127;
  const int b = idx >> 11;
  const float a = -__expf(alog[d * NS_ + n]);
  float hs = 0.f;
  size_t o = (size_t)b * NC_ * DM_ + d;
  float he = hend[o * NS_ + n], ss = Ssum[o];
  for (int c = 0; c < NC_; ++c) {
    const size_t on = o + DM_;
    float hen = 0.f, ssn = 0.f;
    if (c + 1 < NC_) { hen = hend[on * NS_ + n]; ssn = Ssum[on]; }
    hstart[o * NS_ + n] = hs;
    hs = he + __expf(a * ss) * hs;
    he = hen; ss = ssn; o = on;
  }
}

// phase 3: recompute h from h_start, y = (sum_n h*C + u*Dp) * silu(z), bf16 out.
__global__ __launch_bounds__(128) void scan_y(
    const ushort* __restrict__ delta, const ushort* __restrict__ u,
    const ushort* __restrict__ zb, const ushort* __restrict__ BCb,
    const float* __restrict__ alog, const float* __restrict__ Dpv,
    const float* __restrict__ hstart, ushort* __restrict__ y)
{
  __shared__ float bcs[CL_][32];
  const int d = threadIdx.x;
  const int chunk = blockIdx.x, b = blockIdx.y;
  const size_t rowbase = (size_t)b * L_ + (size_t)chunk * CL_;
  {
    ushort8v v = *(const ushort8v*)(BCb + rowbase * 32 + (size_t)d * 8);
    float* dst = &bcs[0][0] + d * 8;
#pragma unroll
    for (int j = 0; j < 8; ++j) dst[j] = bf2f(v[j]);
  }
  float a[NS_], h[NS_];
  const size_t o = ((size_t)b * NC_ + chunk) * DM_ + d;
  const float4* hp = (const float4*)(hstart + o * NS_);
#pragma unroll
  for (int q = 0; q < 4; ++q) {
    float4 v = hp[q];
    h[q * 4] = v.x; h[q * 4 + 1] = v.y; h[q * 4 + 2] = v.z; h[q * 4 + 3] = v.w;
  }
#pragma unroll
  for (int n = 0; n < NS_; ++n) a[n] = -__expf(alog[d * NS_ + n]);
  const float Dd = Dpv[d];
  __syncthreads();
  float dlt = bf2f(delta[rowbase * DM_ + d]);
  float uu  = bf2f(u[rowbase * DM_ + d]);
  float zz  = bf2f(zb[rowbase * DM_ + d]);
  for (int s = 0; s < CL_; ++s) {
    float dn = 0.f, un = 0.f, zn = 0.f;
    if (s + 1 < CL_) {
      dn = bf2f(delta[(rowbase + s + 1) * DM_ + d]);
      un = bf2f(u[(rowbase + s + 1) * DM_ + d]);
      zn = bf2f(zb[(rowbase + s + 1) * DM_ + d]);
    }
    float Bv[NS_], Cv[NS_];
#pragma unroll
    for (int q = 0; q < 4; ++q) {
      *(float4*)&Bv[q * 4] = *(const float4*)&bcs[s][q * 4];
      *(float4*)&Cv[q * 4] = *(const float4*)&bcs[s][16 + q * 4];
    }
    const float du = dlt * uu;
    float yv = uu * Dd;
#pragma unroll
    for (int n = 0; n < NS_; ++n) {
      float dA = __expf(dlt * a[n]);
      h[n] = fmaf(h[n], dA, du * Bv[n]);
      yv = fmaf(h[n], Cv[n], yv);
    }
    y[(rowbase + s) * DM_ + d] = f2bf(yv * zz);
    dlt = dn; uu = un; zz = zn;
  }
}

// ---------------------------------------------------------------------------
// LayerNorm + partial mean-pool (h fp32).
// ---------------------------------------------------------------------------
__global__ __launch_bounds__(256) void lnpool1(
    const float* __restrict__ h, float* __restrict__ partial)
{
  const int b = blockIdx.y, ch = blockIdx.x;
  const int tid = threadIdx.x, wave = tid >> 6, lane = tid & 63;
  float a0 = 0.f, a1 = 0.f;
  const int tbase = ch * 256 + wave * 64;
  for (int i = 0; i < 64; ++i) {
    const float* row = h + ((size_t)b * L_ + tbase + i) * DM_;
    float x0 = row[lane], x1 = row[lane + 64];
    float s = x0 + x1, sq = x0 * x0 + x1 * x1;
    for (int off = 32; off; off >>= 1) { s += __shfl_xor(s, off); sq += __shfl_xor(sq, off); }
    float mu = s * (1.f / 128.f);
    float var = sq * (1.f / 128.f) - mu * mu;
    float rstd = rsqrtf(var + 1e-5f);
    a0 += (x0 - mu) * rstd;
    a1 += (x1 - mu) * rstd;
  }
  __shared__ float ps[4][128];
  ps[wave][lane] = a0;
  ps[wave][lane + 64] = a1;
  __syncthreads();
  if (tid < 128)
    partial[((size_t)b * 16 + ch) * DM_ + tid] = ps[0][tid] + ps[1][tid] + ps[2][tid] + ps[3][tid];
}

// Final reduce + LN affine + classifier head. One block.
__global__ __launch_bounds__(256) void headk(
    const float* __restrict__ partial,
    const float* __restrict__ lng, const float* __restrict__ lnb,
    const float* __restrict__ c1w, const float* __restrict__ c1b,
    const float* __restrict__ c2w, const float* __restrict__ c2b,
    float* __restrict__ out)
{
  __shared__ float pool[16][128];
  __shared__ float p1[16][64];
  const int tid = threadIdx.x;
  for (int i = tid; i < 16 * 128; i += 256) {
    int b = i >> 7, dd = i & 127;
    float s = 0.f;
    for (int c = 0; c < 16; ++c) s += partial[((size_t)b * 16 + c) * DM_ + dd];
    pool[b][dd] = s * (1.f / (float)L_) * lng[dd] + lnb[dd];
  }
  __syncthreads();
  for (int i = tid; i < 16 * 64; i += 256) {
    int b = i >> 6, j = i & 63;
    float acc = c1b[j];
    for (int dd = 0; dd < 128; ++dd) acc += pool[b][dd] * c1w[j * 128 + dd];
    p1[b][j] = fmaxf(acc, 0.f);
  }
  __syncthreads();
  if (tid < 32) {
    int b = tid >> 1, k = tid & 1;
    float acc = c2b[k];
    for (int j = 0; j < 64; ++j) acc += p1[b][j] * c2w[k * 64 + j];
    out[b * 2 + k] = acc;
  }
}

// ---------------------------------------------------------------------------
extern "C" void kernel_launch(void* const* d_in, const int* in_sizes, int n_in,
                              void* d_out, int out_size, void* d_ws, size_t ws_size,
                              hipStream_t stream)
{
  (void)in_sizes; (void)n_in; (void)out_size; (void)ws_size;
  const float* x    = (const float*)d_in[0];
  const float* ipw  = (const float*)d_in[1];
  const float* ipb  = (const float*)d_in[2];
  const float* inw  = (const float*)d_in[3];
  const float* cw   = (const float*)d_in[4];
  const float* cb   = (const float*)d_in[5];
  const float* xpw  = (const float*)d_in[6];
  const float* dtw  = (const float*)d_in[7];
  const float* dtb  = (const float*)d_in[8];
  const float* alog = (const float*)d_in[9];
  const float* Dpv  = (const float*)d_in[10];
  const float* outw = (const float*)d_in[11];
  const float* lng  = (const float*)d_in[12];
  const float* lnb  = (const float*)d_in[13];
  const float* c1w  = (const float*)d_in[14];
  const float* c1b  = (const float*)d_in[15];
  const float* c2w  = (const float*)d_in[16];
  const float* c2b  = (const float*)d_in[17];

  float* ws = (float*)d_ws;
  const size_t SZ = (size_t)M_ * DM_;            // 8,388,608
  float* h      = ws;                            // [M,128] fp32 residual stream
  float* hend   = h + SZ;                        // [B,NC,DM,16]
  float* hstart = hend + (size_t)B_ * NC_ * DM_ * NS_;
  float* Ssum   = hstart + (size_t)B_ * NC_ * DM_ * NS_;  // [B,NC,DM]
  float* part   = Ssum + (size_t)B_ * NC_ * DM_;          // [B,16,DM]
  ushort* bfb   = (ushort*)(part + (size_t)B_ * 16 * DM_);
  ushort* urawb = bfb;                           // [M,128]
  ushort* ub    = urawb + SZ;                    // [M,128]
  ushort* zbuf  = ub + SZ;                       // [M,128]
  ushort* dbuf  = zbuf + SZ;                     // [M,128]
  ushort* ybuf  = dbuf + SZ;                     // [M,128]
  ushort* bcb   = ybuf + SZ;                     // [M,32]
  ushort* wipb  = bcb + (size_t)M_ * 32;         // 128*1280
  ushort* winb  = wipb + (size_t)DM_ * DIN_;     // NL*256*128
  ushort* woutb = winb + (size_t)NL_ * 2 * DM_ * DM_;  // NL*128*128

  // weight pre-conversion (inputs restored every call -> must redo each call)
  wcvt<<<(DM_ * DIN_ / 4 + 255) / 256, 256, 0, stream>>>(ipw, wipb, DM_ * DIN_);
  wcvt<<<(NL_ * 2 * DM_ * DM_ / 4 + 255) / 256, 256, 0, stream>>>(inw, winb, NL_ * 2 * DM_ * DM_);
  wcvt<<<(NL_ * DM_ * DM_ / 4 + 255) / 256, 256, 0, stream>>>(outw, woutb, NL_ * DM_ * DM_);

  // input projection: h = x @ ip_w^T + ip_b  (fp32 A, fp32 C0)
  gemm_bf<<<dim3(1, M_ / 128), 256, 0, stream>>>(
      x, nullptr, wipb, ipb, h, nullptr, nullptr, DM_, DIN_, DM_, 0);

  for (int l = 0; l < NL_; ++l) {
    // in_proj -> u_raw bf16 (cols 0..127), silu(z) bf16 (cols 128..255)
    gemm_bf<<<dim3(2, M_ / 128), 256, 0, stream>>>(
        h, nullptr, winb + (size_t)l * 2 * DM_ * DM_, nullptr,
        nullptr, urawb, zbuf, 2 * DM_, DM_, DM_, 0);
    xpc<<<M_ / 32, 256, 0, stream>>>(
        urawb, cw + l * DM_ * 2, cb + l * DM_,
        xpw + l * (RR_ + 2 * NS_) * DM_, dtw + l * DM_ * RR_, dtb + l * DM_,
        ub, dbuf, bcb);
    scan_h<<<dim3(NC_, B_), 128, 0, stream>>>(
        dbuf, ub, bcb, alog + l * DM_ * NS_, hend, Ssum);
    scan_comb<<<(B_ * DM_ * NS_) / 256, 256, 0, stream>>>(
        hend, Ssum, alog + l * DM_ * NS_, hstart);
    scan_y<<<dim3(NC_, B_), 128, 0, stream>>>(
        dbuf, ub, zbuf, bcb, alog + l * DM_ * NS_, Dpv + l * DM_, hstart, ybuf);
    // out_proj with fused residual: h += y @ out_w^T  (bf16 A, fp32 C0)
    gemm_bf<<<dim3(1, M_ / 128), 256, 0, stream>>>(
        nullptr, ybuf, woutb + (size_t)l * DM_ * DM_, nullptr,
        h, nullptr, nullptr, DM_, DM_, DM_, 1);
  }

  lnpool1<<<dim3(16, B_), 256, 0, stream>>>(h, part);
  headk<<<1, 256, 0, stream>>>(part, lng, lnb, c1w, c1b, c2w, c2b, (float*)d_out);
}